// Round 1
// baseline (406.348 us; speedup 1.0000x reference)
//
#include <hip/hip_runtime.h>

#define NODE 400
#define POP 3
#define TRS 40
#define STEPS 10
#define DMAX 500
#define OUT 64
#define DT 0.1f
#define JPL 7  // ceil(NODE/64) j-indices per lane

__device__ __forceinline__ float relu_(float x) { return x > 0.f ? x : 0.f; }

// ---------------------------------------------------------------------------
// Kernel A: Frobenius sum-of-squares for the three effective weight matrices.
// acc[0] = ||exp(w_bb)*sc||^2, acc[1] = ||exp(w_ff)*sc||^2,
// acc[2] = ||0.5*(exp(w_ll)*sc + (exp(w_ll)*sc)^T)||^2
// ---------------------------------------------------------------------------
__global__ __launch_bounds__(256) void ssq_kernel(
    const float* __restrict__ wbb, const float* __restrict__ wff,
    const float* __restrict__ wll, const float* __restrict__ sc,
    float* __restrict__ acc) {
  int idx = blockIdx.x * 256 + threadIdx.x;
  float eb = 0.f, ef = 0.f, el = 0.f;
  if (idx < NODE * NODE) {
    int i = idx / NODE, j = idx - i * NODE;
    int ji = j * NODE + i;
    float scij = sc[idx];
    float b = expf(wbb[idx]) * scij;
    float f = expf(wff[idx]) * scij;
    float l = 0.5f * (expf(wll[idx]) * scij + expf(wll[ji]) * sc[ji]);
    eb = b * b; ef = f * f; el = l * l;
  }
  // wave butterfly then cross-wave via LDS
  for (int m = 32; m; m >>= 1) {
    eb += __shfl_xor(eb, m, 64);
    ef += __shfl_xor(ef, m, 64);
    el += __shfl_xor(el, m, 64);
  }
  __shared__ float red[3][4];
  int lane = threadIdx.x & 63, wv = threadIdx.x >> 6;
  if (lane == 0) { red[0][wv] = eb; red[1][wv] = ef; red[2][wv] = el; }
  __syncthreads();
  if (threadIdx.x == 0) {
    atomicAdd(&acc[0], red[0][0] + red[0][1] + red[0][2] + red[0][3]);
    atomicAdd(&acc[1], red[1][0] + red[1][1] + red[1][2] + red[1][3]);
    atomicAdd(&acc[2], red[2][0] + red[2][1] + red[2][2] + red[2][3]);
  }
}

// ---------------------------------------------------------------------------
// Kernel B: per-node simulation. One 64-lane wave per node; 400 blocks.
// Nodes are fully decoupled (Ed[i,j] = hE[i, delays[i,j]] reads row i only).
// History is an LDS ring buffer; weights/delays live in VGPRs.
// Single-wave block => LDS ops are in program order, no per-step barriers.
// ---------------------------------------------------------------------------
__global__ __launch_bounds__(64) void sim_kernel(
    const float* __restrict__ external, const float* __restrict__ hx,
    const float* __restrict__ hE, const float* __restrict__ sc,
    const float* __restrict__ dist, const float* __restrict__ wbb,
    const float* __restrict__ wff, const float* __restrict__ wll,
    const float* __restrict__ theta, const float* __restrict__ ssq,
    float* __restrict__ vsnap) {
  const int node = blockIdx.x;
  const int lane = threadIdx.x;

  __shared__ float ring[DMAX];
  __shared__ float u_lds[STEPS * TRS];

  // --- parameters (uniform scalar loads) ---
  const float VL = relu_(theta[0]), VI = relu_(theta[1]);
  const float VE = relu_(theta[2]), VNMDA = relu_(theta[3]);
  const float alpha_mg = relu_(theta[4]), VR = relu_(theta[5]);
  const float pi_sigma = relu_(theta[6]);
  const float gLp = relu_(theta[7]), Cc = relu_(theta[8]), kappa = relu_(theta[9]);
  const float g_gE = relu_(theta[10]), g_gE_sc = relu_(theta[11]);
  const float g_gI = relu_(theta[12]), g_gI_sc = relu_(theta[13]);
  const float g_gN = relu_(theta[14]), g_gN_sc = relu_(theta[15]);
  const float g_k = relu_(theta[16]);
  const float mu = 0.1f + relu_(theta[20]);
  const float uk = relu_(theta[21]) * theta[23];  // k * ki
  const float g_l = relu_(theta[24]), g_f = relu_(theta[25]), g_b = relu_(theta[26]);
  const float inv_nb = 1.f / sqrtf(ssq[0]);
  const float inv_nf = 1.f / sqrtf(ssq[1]);
  const float inv_nl = 1.f / sqrtf(ssq[2]);
  const float invC = 1.f / Cc;
  const float dk = DT * kappa;

  // --- stage history + external drive into LDS ---
  for (int d = lane; d < DMAX; d += 64) ring[d] = hE[node * DMAX + d];
  for (int t = lane; t < STEPS * TRS; t += 64)
    u_lds[t] = external[node * STEPS * TRS + t];

  // --- per-lane normalized weights + delays (registers) ---
  float wl[JPL], wfv[JPL], wbv[JPL];
  int dl[JPL];
  float pl = 0.f, pf = 0.f, pb = 0.f;
#pragma unroll
  for (int kj = 0; kj < JPL; ++kj) {
    int j = lane + kj * 64;
    float vl = 0.f, vf = 0.f, vb = 0.f;
    int dd = 0;
    if (j < NODE) {
      int ij = node * NODE + j;
      int ji = j * NODE + node;
      float scij = sc[ij];
      vb = expf(wbb[ij]) * scij * inv_nb;
      vf = expf(wff[ij]) * scij * inv_nf;
      vl = 0.5f * (expf(wll[ij]) * scij + expf(wll[ji]) * sc[ji]) * inv_nl;
      dd = (int)(dist[ij] / mu);
      if (dd < 0) dd = 0;
      if (dd > DMAX - 1) dd = DMAX - 1;
    }
    wl[kj] = vl; wfv[kj] = vf; wbv[kj] = vb; dl[kj] = dd;
    pl += vl; pf += vf; pb += vb;
  }
  // row sums rs_* (replicated in all lanes)
  for (int m = 32; m; m >>= 1) {
    pl += __shfl_xor(pl, m, 64);
    pf += __shfl_xor(pf, m, 64);
    pb += __shfl_xor(pb, m, 64);
  }
  const float rs_l = __shfl(pl, 0, 64);
  const float rs_f = __shfl(pf, 0, 64);
  const float rs_b = __shfl(pb, 0, 64);

  // --- initial state, replicated in every lane (hx: [node][pop][state]) ---
  const int hb = node * POP * 4;
  float V0 = hx[hb + 0], V1 = hx[hb + 4], V2 = hx[hb + 8];
  float E0 = hx[hb + 1], E1 = hx[hb + 5], E2 = hx[hb + 9];
  float I0 = hx[hb + 2], I1 = hx[hb + 6], I2 = hx[hb + 10];
  float N0 = hx[hb + 3], N1 = hx[hb + 7], N2 = hx[hb + 11];

  __syncthreads();  // staging done (single wave, but keep for compiler clarity)

  int head = 0;  // logical index d lives at physical (head + d) % DMAX
  for (int tr = 0; tr < TRS; ++tr) {
    for (int st = 0; st < STEPS; ++st) {
      // firing rates from pre-update V
      float sE = 1.f / (1.f + __expf(-pi_sigma * (V0 - VR)));
      float sI = 1.f / (1.f + __expf(-pi_sigma * (V1 - VR)));
      float sP = 1.f / (1.f + __expf(-pi_sigma * (V2 - VR)));

      // delayed-history gather + 3 weighted sums
      float al = 0.f, af = 0.f, ab = 0.f;
#pragma unroll
      for (int kj = 0; kj < JPL; ++kj) {
        int a = head + dl[kj];
        if (a >= DMAX) a -= DMAX;
        float E = ring[a];
        al = fmaf(wl[kj], E, al);
        af = fmaf(wfv[kj], E, af);
        ab = fmaf(wbv[kj], E, ab);
      }
      for (int m = 32; m; m >>= 1) {
        al += __shfl_xor(al, m, 64);
        af += __shfl_xor(af, m, 64);
        ab += __shfl_xor(ab, m, 64);
      }
      al = __shfl(al, 0, 64);  // keep all lanes bit-identical
      af = __shfl(af, 0, 64);
      ab = __shfl(ab, 0, 64);

      float lr_l = g_l * (al - rs_l * sP);
      float lr_f = g_f * (af - rs_f * sP);
      float lr_b = g_b * (ab - rs_b * sP);
      float u = uk * u_lds[st * TRS + tr];

      float ex0 = g_gE * sP + lr_l + u;
      float ex1 = g_gE_sc * sE + lr_b;
      float ex2 = g_k * sE + lr_f + u;
      float in0 = g_gI * sI, in1 = g_gI_sc * sI, in2 = g_gI * sI;
      float nm0 = g_gN * sP + lr_l;
      float nm1 = g_gN_sc * sE;
      float nm2 = g_gN * sE;

      float m0 = 1.f / (1.f + 0.2f * __expf(-alpha_mg * V0));
      float m1 = 1.f / (1.f + 0.2f * __expf(-alpha_mg * V1));
      float m2 = 1.f / (1.f + 0.2f * __expf(-alpha_mg * V2));

      float dV0 = (gLp * (-VL - V0) + E0 * (VE - V0) + I0 * (-VI - V0) +
                   N0 * m0 * (VNMDA - V0)) * invC;
      float dV1 = (gLp * (-VL - V1) + E1 * (VE - V1) + I1 * (-VI - V1) +
                   N1 * m1 * (VNMDA - V1)) * invC;
      float dV2 = (gLp * (-VL - V2) + E2 * (VE - V2) + I2 * (-VI - V2) +
                   N2 * m2 * (VNMDA - V2)) * invC;

      V0 += DT * dV0; V1 += DT * dV1; V2 += DT * dV2;
      E0 += dk * (ex0 - E0); E1 += dk * (ex1 - E1); E2 += dk * (ex2 - E2);
      I0 += dk * (in0 - I0); I1 += dk * (in1 - I1); I2 += dk * (in2 - I2);
      N0 += dk * (nm0 - N0); N1 += dk * (nm1 - N1); N2 += dk * (nm2 - N2);

      // push sP at logical front: head-- (mod), write slot.
      // Single-wave block: LDS ops execute in program order -> no barrier.
      head = (head == 0) ? (DMAX - 1) : (head - 1);
      if (lane == 0) ring[head] = sP;
    }
    if (lane == 0) vsnap[tr * NODE + node] = V2;
  }
}

// ---------------------------------------------------------------------------
// Kernel C: EEG readout. eeg[tr,o] = cy0 * sum_n (lm[o,n]-colmean[n])*V2[tr,n] - y0
// ---------------------------------------------------------------------------
__global__ __launch_bounds__(256) void eeg_kernel(
    const float* __restrict__ lm, const float* __restrict__ vsnap,
    const float* __restrict__ theta, float* __restrict__ out) {
  int tr = blockIdx.x;
  __shared__ float cm[NODE];
  __shared__ float vs[NODE];
  int tid = threadIdx.x;
  for (int n = tid; n < NODE; n += 256) {
    float s = 0.f;
    for (int o = 0; o < OUT; ++o) s += lm[o * NODE + n];  // coalesced over tid
    cm[n] = s * (1.f / OUT);
    vs[n] = vsnap[tr * NODE + n];
  }
  __syncthreads();
  if (tid < OUT) {
    float cy0 = theta[22], y0 = theta[19];
    float acc = 0.f;
    for (int n = 0; n < NODE; ++n)
      acc = fmaf(lm[tid * NODE + n] - cm[n], vs[n], acc);
    out[tr * OUT + tid] = cy0 * acc - y0;
  }
}

extern "C" void kernel_launch(void* const* d_in, const int* in_sizes, int n_in,
                              void* d_out, int out_size, void* d_ws, size_t ws_size,
                              hipStream_t stream) {
  const float* external = (const float*)d_in[0];  // (NODE, STEPS, TRS)
  const float* hx       = (const float*)d_in[1];  // (NODE, POP, STATE)
  const float* hE       = (const float*)d_in[2];  // (NODE, DMAX)
  const float* sc       = (const float*)d_in[3];  // (NODE, NODE)
  const float* dist     = (const float*)d_in[4];  // (NODE, NODE)
  const float* wbb      = (const float*)d_in[5];
  const float* wff      = (const float*)d_in[6];
  const float* wll      = (const float*)d_in[7];
  const float* lm       = (const float*)d_in[8];  // (OUT, NODE)
  const float* theta    = (const float*)d_in[9];  // (27,)
  float* out = (float*)d_out;                     // (TRS, OUT)

  float* acc = (float*)d_ws;       // [0..2] sum-of-squares accumulators
  float* vsnap = acc + 16;         // TRS*NODE snapshot of V[:,2] per trial

  hipMemsetAsync(d_ws, 0, 16 * sizeof(float), stream);
  ssq_kernel<<<(NODE * NODE + 255) / 256, 256, 0, stream>>>(wbb, wff, wll, sc, acc);
  sim_kernel<<<NODE, 64, 0, stream>>>(external, hx, hE, sc, dist, wbb, wff, wll,
                                      theta, acc, vsnap);
  eeg_kernel<<<TRS, 256, 0, stream>>>(lm, vsnap, theta, out);
}

// Round 2
// 330.373 us; speedup vs baseline: 1.2300x; 1.2300x over previous
//
#include <hip/hip_runtime.h>

#define NODE 400
#define POP 3
#define TRS 40
#define STEPS 10
#define DMAX 500
#define OUT 64
#define DT 0.1f
#define JPL 7  // ceil(NODE/64) j-indices per lane

__device__ __forceinline__ float relu_(float x) { return x > 0.f ? x : 0.f; }

// ---- DPP wave64 reduction: row_shr 1/2/4/8 + row_bcast15/31, total in lane63.
template <int CTRL>
__device__ __forceinline__ float dpp_mov(float x) {
  int r = __builtin_amdgcn_update_dpp(0, __builtin_bit_cast(int, x), CTRL,
                                      0xf, 0xf, true);
  return __builtin_bit_cast(float, r);
}

// Reduce three values simultaneously (ILP across the 3 dependent chains);
// returns totals broadcast to all lanes via readlane (SGPR).
__device__ __forceinline__ void wave_reduce3(float& a, float& b, float& c) {
  a += dpp_mov<0x111>(a); b += dpp_mov<0x111>(b); c += dpp_mov<0x111>(c);
  a += dpp_mov<0x112>(a); b += dpp_mov<0x112>(b); c += dpp_mov<0x112>(c);
  a += dpp_mov<0x114>(a); b += dpp_mov<0x114>(b); c += dpp_mov<0x114>(c);
  a += dpp_mov<0x118>(a); b += dpp_mov<0x118>(b); c += dpp_mov<0x118>(c);
  a += dpp_mov<0x142>(a); b += dpp_mov<0x142>(b); c += dpp_mov<0x142>(c);
  a += dpp_mov<0x143>(a); b += dpp_mov<0x143>(b); c += dpp_mov<0x143>(c);
  a = __builtin_bit_cast(float, __builtin_amdgcn_readlane(__builtin_bit_cast(int, a), 63));
  b = __builtin_bit_cast(float, __builtin_amdgcn_readlane(__builtin_bit_cast(int, b), 63));
  c = __builtin_bit_cast(float, __builtin_amdgcn_readlane(__builtin_bit_cast(int, c), 63));
}

// ---------------------------------------------------------------------------
// Kernel A: Frobenius sum-of-squares for the three effective weight matrices.
// ---------------------------------------------------------------------------
__global__ __launch_bounds__(256) void ssq_kernel(
    const float* __restrict__ wbb, const float* __restrict__ wff,
    const float* __restrict__ wll, const float* __restrict__ sc,
    float* __restrict__ acc) {
  int idx = blockIdx.x * 256 + threadIdx.x;
  float eb = 0.f, ef = 0.f, el = 0.f;
  if (idx < NODE * NODE) {
    int i = idx / NODE, j = idx - i * NODE;
    int ji = j * NODE + i;
    float scij = sc[idx];
    float b = expf(wbb[idx]) * scij;
    float f = expf(wff[idx]) * scij;
    float l = 0.5f * (expf(wll[idx]) * scij + expf(wll[ji]) * sc[ji]);
    eb = b * b; ef = f * f; el = l * l;
  }
  wave_reduce3(eb, ef, el);
  __shared__ float red[3][4];
  int lane = threadIdx.x & 63, wv = threadIdx.x >> 6;
  if (lane == 0) { red[0][wv] = eb; red[1][wv] = ef; red[2][wv] = el; }
  __syncthreads();
  if (threadIdx.x == 0) {
    atomicAdd(&acc[0], red[0][0] + red[0][1] + red[0][2] + red[0][3]);
    atomicAdd(&acc[1], red[1][0] + red[1][1] + red[1][2] + red[1][3]);
    atomicAdd(&acc[2], red[2][0] + red[2][1] + red[2][2] + red[2][3]);
  }
}

// ---------------------------------------------------------------------------
// Kernel B: per-node simulation. One 64-lane wave per node; 400 blocks.
// Nodes fully decoupled (Ed[i,j] = hE[i, delays[i,j]] reads row i only).
// LDS ring buffer for history; weights/delays in VGPRs; DPP reductions.
// Single-wave block => LDS ops in program order, no per-step barriers.
// ---------------------------------------------------------------------------
__global__ __launch_bounds__(64) void sim_kernel(
    const float* __restrict__ external, const float* __restrict__ hx,
    const float* __restrict__ hE, const float* __restrict__ sc,
    const float* __restrict__ dist, const float* __restrict__ wbb,
    const float* __restrict__ wff, const float* __restrict__ wll,
    const float* __restrict__ theta, const float* __restrict__ ssq,
    float* __restrict__ vsnap) {
  const int node = blockIdx.x;
  const int lane = threadIdx.x;

  __shared__ float ring[DMAX];
  __shared__ float u_lds[STEPS * TRS];

  // --- parameters (uniform scalar loads) ---
  const float VL = relu_(theta[0]), VI = relu_(theta[1]);
  const float VE = relu_(theta[2]), VNMDA = relu_(theta[3]);
  const float alpha_mg = relu_(theta[4]), VR = relu_(theta[5]);
  const float pi_sigma = relu_(theta[6]);
  const float gLp = relu_(theta[7]), Cc = relu_(theta[8]), kappa = relu_(theta[9]);
  const float g_gE = relu_(theta[10]), g_gE_sc = relu_(theta[11]);
  const float g_gI = relu_(theta[12]), g_gI_sc = relu_(theta[13]);
  const float g_gN = relu_(theta[14]), g_gN_sc = relu_(theta[15]);
  const float g_k = relu_(theta[16]);
  const float mu = 0.1f + relu_(theta[20]);
  const float uk = relu_(theta[21]) * theta[23];  // k * ki
  const float g_l = relu_(theta[24]), g_f = relu_(theta[25]), g_b = relu_(theta[26]);
  const float inv_nb = 1.f / sqrtf(ssq[0]);
  const float inv_nf = 1.f / sqrtf(ssq[1]);
  const float inv_nl = 1.f / sqrtf(ssq[2]);
  const float invC = 1.f / Cc;
  const float dk = DT * kappa;

  // --- stage history + external drive into LDS ---
  for (int d = lane; d < DMAX; d += 64) ring[d] = hE[node * DMAX + d];
  for (int t = lane; t < STEPS * TRS; t += 64)
    u_lds[t] = external[node * STEPS * TRS + t];

  // --- per-lane normalized weights + delays (registers) ---
  float wl[JPL], wfv[JPL], wbv[JPL];
  int dl[JPL];
  float pl = 0.f, pf = 0.f, pb = 0.f;
#pragma unroll
  for (int kj = 0; kj < JPL; ++kj) {
    int j = lane + kj * 64;
    float vl = 0.f, vf = 0.f, vb = 0.f;
    int dd = 0;
    if (j < NODE) {
      int ij = node * NODE + j;
      int ji = j * NODE + node;
      float scij = sc[ij];
      vb = expf(wbb[ij]) * scij * inv_nb;
      vf = expf(wff[ij]) * scij * inv_nf;
      vl = 0.5f * (expf(wll[ij]) * scij + expf(wll[ji]) * sc[ji]) * inv_nl;
      dd = (int)(dist[ij] / mu);
      if (dd < 0) dd = 0;
      if (dd > DMAX - 1) dd = DMAX - 1;
    }
    wl[kj] = vl; wfv[kj] = vf; wbv[kj] = vb; dl[kj] = dd;
    pl += vl; pf += vf; pb += vb;
  }
  wave_reduce3(pl, pf, pb);
  const float rs_l = pl, rs_f = pf, rs_b = pb;

  // --- initial state, replicated in every lane (hx: [node][pop][state]) ---
  const int hb = node * POP * 4;
  float V0 = hx[hb + 0], V1 = hx[hb + 4], V2 = hx[hb + 8];
  float E0 = hx[hb + 1], E1 = hx[hb + 5], E2 = hx[hb + 9];
  float I0 = hx[hb + 2], I1 = hx[hb + 6], I2 = hx[hb + 10];
  float N0 = hx[hb + 3], N1 = hx[hb + 7], N2 = hx[hb + 11];

  __syncthreads();

  int head = 0;  // logical index d lives at physical (head + d) % DMAX
  for (int tr = 0; tr < TRS; ++tr) {
    // one uniform LDS read per trial; per-step value fetched via readlane
    float u_tr = (lane < STEPS) ? u_lds[lane * TRS + tr] : 0.f;
    for (int st = 0; st < STEPS; ++st) {
      // 1) issue the delayed-history gather FIRST (hide ~120cyc under exp)
      float Ev[JPL];
#pragma unroll
      for (int kj = 0; kj < JPL; ++kj) {
        int a = head + dl[kj];
        if (a >= DMAX) a -= DMAX;
        Ev[kj] = ring[a];
      }

      // 2) sigmoids from pre-update V (overlaps with LDS loads)
      float sE = 1.f / (1.f + __expf(-pi_sigma * (V0 - VR)));
      float sI = 1.f / (1.f + __expf(-pi_sigma * (V1 - VR)));
      float sP = 1.f / (1.f + __expf(-pi_sigma * (V2 - VR)));
      float m0 = 1.f / (1.f + 0.2f * __expf(-alpha_mg * V0));
      float m1 = 1.f / (1.f + 0.2f * __expf(-alpha_mg * V1));
      float m2 = 1.f / (1.f + 0.2f * __expf(-alpha_mg * V2));

      // 3) weighted sums over this lane's j-slice
      float al = 0.f, af = 0.f, ab = 0.f;
#pragma unroll
      for (int kj = 0; kj < JPL; ++kj) {
        al = fmaf(wl[kj], Ev[kj], al);
        af = fmaf(wfv[kj], Ev[kj], af);
        ab = fmaf(wbv[kj], Ev[kj], ab);
      }

      // 4) DPP reduce (VALU-latency, no LDS round-trips)
      wave_reduce3(al, af, ab);

      // 5) scalar dynamics (replicated across lanes)
      float lr_l = g_l * (al - rs_l * sP);
      float lr_f = g_f * (af - rs_f * sP);
      float lr_b = g_b * (ab - rs_b * sP);
      float u = uk * __builtin_bit_cast(
                         float, __builtin_amdgcn_readlane(
                                    __builtin_bit_cast(int, u_tr), st));

      float ex0 = g_gE * sP + lr_l + u;
      float ex1 = g_gE_sc * sE + lr_b;
      float ex2 = g_k * sE + lr_f + u;
      float in0 = g_gI * sI, in1 = g_gI_sc * sI, in2 = g_gI * sI;
      float nm0 = g_gN * sP + lr_l;
      float nm1 = g_gN_sc * sE;
      float nm2 = g_gN * sE;

      float dV0 = (gLp * (-VL - V0) + E0 * (VE - V0) + I0 * (-VI - V0) +
                   N0 * m0 * (VNMDA - V0)) * invC;
      float dV1 = (gLp * (-VL - V1) + E1 * (VE - V1) + I1 * (-VI - V1) +
                   N1 * m1 * (VNMDA - V1)) * invC;
      float dV2 = (gLp * (-VL - V2) + E2 * (VE - V2) + I2 * (-VI - V2) +
                   N2 * m2 * (VNMDA - V2)) * invC;

      V0 += DT * dV0; V1 += DT * dV1; V2 += DT * dV2;
      E0 += dk * (ex0 - E0); E1 += dk * (ex1 - E1); E2 += dk * (ex2 - E2);
      I0 += dk * (in0 - I0); I1 += dk * (in1 - I1); I2 += dk * (in2 - I2);
      N0 += dk * (nm0 - N0); N1 += dk * (nm1 - N1); N2 += dk * (nm2 - N2);

      // 6) push sP at logical front (single-wave: LDS in program order)
      head = (head == 0) ? (DMAX - 1) : (head - 1);
      if (lane == 0) ring[head] = sP;
    }
    if (lane == 0) vsnap[tr * NODE + node] = V2;
  }
}

// ---------------------------------------------------------------------------
// Kernel C: EEG readout. eeg[tr,o] = cy0 * sum_n (lm[o,n]-colmean[n])*V2[tr,n] - y0
// ---------------------------------------------------------------------------
__global__ __launch_bounds__(256) void eeg_kernel(
    const float* __restrict__ lm, const float* __restrict__ vsnap,
    const float* __restrict__ theta, float* __restrict__ out) {
  int tr = blockIdx.x;
  __shared__ float cm[NODE];
  __shared__ float vs[NODE];
  int tid = threadIdx.x;
  for (int n = tid; n < NODE; n += 256) {
    float s = 0.f;
    for (int o = 0; o < OUT; ++o) s += lm[o * NODE + n];  // coalesced over tid
    cm[n] = s * (1.f / OUT);
    vs[n] = vsnap[tr * NODE + n];
  }
  __syncthreads();
  if (tid < OUT) {
    float cy0 = theta[22], y0 = theta[19];
    float acc = 0.f;
    for (int n = 0; n < NODE; ++n)
      acc = fmaf(lm[tid * NODE + n] - cm[n], vs[n], acc);
    out[tr * OUT + tid] = cy0 * acc - y0;
  }
}

extern "C" void kernel_launch(void* const* d_in, const int* in_sizes, int n_in,
                              void* d_out, int out_size, void* d_ws, size_t ws_size,
                              hipStream_t stream) {
  const float* external = (const float*)d_in[0];  // (NODE, STEPS, TRS)
  const float* hx       = (const float*)d_in[1];  // (NODE, POP, STATE)
  const float* hE       = (const float*)d_in[2];  // (NODE, DMAX)
  const float* sc       = (const float*)d_in[3];  // (NODE, NODE)
  const float* dist     = (const float*)d_in[4];  // (NODE, NODE)
  const float* wbb      = (const float*)d_in[5];
  const float* wff      = (const float*)d_in[6];
  const float* wll      = (const float*)d_in[7];
  const float* lm       = (const float*)d_in[8];  // (OUT, NODE)
  const float* theta    = (const float*)d_in[9];  // (27,)
  float* out = (float*)d_out;                     // (TRS, OUT)

  float* acc = (float*)d_ws;       // [0..2] sum-of-squares accumulators
  float* vsnap = acc + 16;         // TRS*NODE snapshot of V[:,2] per trial

  hipMemsetAsync(d_ws, 0, 16 * sizeof(float), stream);
  ssq_kernel<<<(NODE * NODE + 255) / 256, 256, 0, stream>>>(wbb, wff, wll, sc, acc);
  sim_kernel<<<NODE, 64, 0, stream>>>(external, hx, hE, sc, dist, wbb, wff, wll,
                                      theta, acc, vsnap);
  eeg_kernel<<<TRS, 256, 0, stream>>>(lm, vsnap, theta, out);
}

// Round 3
// 266.708 us; speedup vs baseline: 1.5236x; 1.2387x over previous
//
#include <hip/hip_runtime.h>

#define NODE 400
#define POP 3
#define TRS 40
#define STEPS 10
#define DMAX 500
#define OUT 64
#define DT 0.1f
#define JPL 7           // ceil(NODE/64) j-indices per lane
#define PAD 64          // front pad so deepest conv read stays in-bounds
#define HIST (PAD + DMAX + TRS * STEPS)   // 964 floats of history
#define WSZ 520         // W[delta] bins, delta in [0, 512]

__device__ __forceinline__ float relu_(float x) { return x > 0.f ? x : 0.f; }
__device__ __forceinline__ float rcp_(float x) { return __builtin_amdgcn_rcpf(x); }

// ---- DPP wave64 reduction: row_shr 1/2/4/8 + row_bcast15/31, total in lane63.
template <int CTRL>
__device__ __forceinline__ float dpp_mov(float x) {
  int r = __builtin_amdgcn_update_dpp(0, __builtin_bit_cast(int, x), CTRL,
                                      0xf, 0xf, true);
  return __builtin_bit_cast(float, r);
}
template <int CTRL>
__device__ __forceinline__ int dpp_movi(int x) {
  return __builtin_amdgcn_update_dpp(0, x, CTRL, 0xf, 0xf, true);
}

__device__ __forceinline__ void wave_reduce3(float& a, float& b, float& c) {
  a += dpp_mov<0x111>(a); b += dpp_mov<0x111>(b); c += dpp_mov<0x111>(c);
  a += dpp_mov<0x112>(a); b += dpp_mov<0x112>(b); c += dpp_mov<0x112>(c);
  a += dpp_mov<0x114>(a); b += dpp_mov<0x114>(b); c += dpp_mov<0x114>(c);
  a += dpp_mov<0x118>(a); b += dpp_mov<0x118>(b); c += dpp_mov<0x118>(c);
  a += dpp_mov<0x142>(a); b += dpp_mov<0x142>(b); c += dpp_mov<0x142>(c);
  a += dpp_mov<0x143>(a); b += dpp_mov<0x143>(b); c += dpp_mov<0x143>(c);
  a = __builtin_bit_cast(float, __builtin_amdgcn_readlane(__builtin_bit_cast(int, a), 63));
  b = __builtin_bit_cast(float, __builtin_amdgcn_readlane(__builtin_bit_cast(int, b), 63));
  c = __builtin_bit_cast(float, __builtin_amdgcn_readlane(__builtin_bit_cast(int, c), 63));
}

__device__ __forceinline__ int wave_max_int(int x) {
  x = max(x, dpp_movi<0x111>(x));
  x = max(x, dpp_movi<0x112>(x));
  x = max(x, dpp_movi<0x114>(x));
  x = max(x, dpp_movi<0x118>(x));
  x = max(x, dpp_movi<0x142>(x));
  x = max(x, dpp_movi<0x143>(x));
  return __builtin_amdgcn_readlane(x, 63);
}

// ---------------------------------------------------------------------------
// Kernel A: Frobenius sum-of-squares for the three effective weight matrices.
// ---------------------------------------------------------------------------
__global__ __launch_bounds__(256) void ssq_kernel(
    const float* __restrict__ wbb, const float* __restrict__ wff,
    const float* __restrict__ wll, const float* __restrict__ sc,
    float* __restrict__ acc) {
  int idx = blockIdx.x * 256 + threadIdx.x;
  float eb = 0.f, ef = 0.f, el = 0.f;
  if (idx < NODE * NODE) {
    int i = idx / NODE, j = idx - i * NODE;
    int ji = j * NODE + i;
    float scij = sc[idx];
    float b = expf(wbb[idx]) * scij;
    float f = expf(wff[idx]) * scij;
    float l = 0.5f * (expf(wll[idx]) * scij + expf(wll[ji]) * sc[ji]);
    eb = b * b; ef = f * f; el = l * l;
  }
  wave_reduce3(eb, ef, el);
  __shared__ float red[3][4];
  int lane = threadIdx.x & 63, wv = threadIdx.x >> 6;
  if (lane == 0) { red[0][wv] = eb; red[1][wv] = ef; red[2][wv] = el; }
  __syncthreads();
  if (threadIdx.x == 0) {
    atomicAdd(&acc[0], red[0][0] + red[0][1] + red[0][2] + red[0][3]);
    atomicAdd(&acc[1], red[1][0] + red[1][1] + red[1][2] + red[1][3]);
    atomicAdd(&acc[2], red[2][0] + red[2][1] + red[2][2] + red[2][3]);
  }
}

// ---------------------------------------------------------------------------
// Kernel B: per-node simulation, convolution form.
//   al(t) = sum_d W[d]*h(t-1-d) = P(t) + W[0]*s(t-1);   P precomputed 1 step
//   ahead (needs only h up to t-2) -> gather+reduce latency is off the
//   loop-carried chain. History is LINEAR in LDS: B[PAD+DMAX-1-d]=hE[d],
//   B[PAD+DMAX+t]=s(t); conv reads are lane-contiguous (conflict-free).
// ---------------------------------------------------------------------------
__global__ __launch_bounds__(64) void sim_kernel(
    const float* __restrict__ external, const float* __restrict__ hx,
    const float* __restrict__ hE, const float* __restrict__ sc,
    const float* __restrict__ dist, const float* __restrict__ wbb,
    const float* __restrict__ wff, const float* __restrict__ wll,
    const float* __restrict__ theta, const float* __restrict__ ssq,
    float* __restrict__ vsnap) {
  const int node = blockIdx.x;
  const int lane = threadIdx.x;

  __shared__ float B[HIST + 64];     // +64 dummy scatter region
  __shared__ float Wl[WSZ], Wf[WSZ], Wb[WSZ];
  __shared__ float u_lds[STEPS * TRS];

  // --- parameters ---
  const float VL = relu_(theta[0]), VI = relu_(theta[1]);
  const float VE = relu_(theta[2]), VNMDA = relu_(theta[3]);
  const float alpha_mg = relu_(theta[4]), VR = relu_(theta[5]);
  const float pi_sigma = relu_(theta[6]);
  const float gLp = relu_(theta[7]), Cc = relu_(theta[8]), kappa = relu_(theta[9]);
  const float g_gE = relu_(theta[10]), g_gE_sc = relu_(theta[11]);
  const float g_gI = relu_(theta[12]), g_gI_sc = relu_(theta[13]);
  const float g_gN = relu_(theta[14]), g_gN_sc = relu_(theta[15]);
  const float g_k = relu_(theta[16]);
  const float mu = 0.1f + relu_(theta[20]);
  const float uk = relu_(theta[21]) * theta[23];
  const float g_l = relu_(theta[24]), g_f = relu_(theta[25]), g_b = relu_(theta[26]);
  const float inv_nb = 1.f / sqrtf(ssq[0]);
  const float inv_nf = 1.f / sqrtf(ssq[1]);
  const float inv_nl = 1.f / sqrtf(ssq[2]);
  const float DTC = DT / Cc;
  const float dk = DT * kappa;
  // sigmoid arg constants: exp(-pi_sigma*(V-VR)) = expf(fma(-ps,V,psVR))
  const float nps = -pi_sigma, psVR = pi_sigma * VR;
  const float nam = -alpha_mg;

  // --- stage LDS ---
  B[lane] = 0.f;                                        // zero front pad
  for (int d = lane; d < DMAX; d += 64) B[PAD + DMAX - 1 - d] = hE[node * DMAX + d];
  for (int k = lane; k < WSZ; k += 64) { Wl[k] = 0.f; Wf[k] = 0.f; Wb[k] = 0.f; }
  for (int t = lane; t < STEPS * TRS; t += 64)
    u_lds[t] = uk * external[node * STEPS * TRS + t];
  __syncthreads();   // single wave; ensures W zeroing ordered before atomics

  // --- bin weights by delay (LDS float atomics), row sums, max delay ---
  float rl = 0.f, rf = 0.f, rb = 0.f;
  int mymax = 0;
#pragma unroll
  for (int kj = 0; kj < JPL; ++kj) {
    int j = lane + kj * 64;
    if (j < NODE) {
      int ij = node * NODE + j;
      int ji = j * NODE + node;
      float scij = sc[ij];
      float vb = expf(wbb[ij]) * scij * inv_nb;
      float vf = expf(wff[ij]) * scij * inv_nf;
      float vl = 0.5f * (expf(wll[ij]) * scij + expf(wll[ji]) * sc[ji]) * inv_nl;
      int dd = (int)(dist[ij] / mu);
      dd = min(max(dd, 0), DMAX - 1);
      atomicAdd(&Wl[dd], vl); atomicAdd(&Wf[dd], vf); atomicAdd(&Wb[dd], vb);
      rl += vl; rf += vf; rb += vb;
      mymax = max(mymax, dd);
    }
  }
  wave_reduce3(rl, rf, rb);
  const float rs_l = rl, rs_f = rf, rs_b = rb;
  const int maxd = wave_max_int(mymax);
  const bool small = (maxd <= 128);   // 2-segment conv covers delta<=128

  __syncthreads();

  // --- per-lane conv weights in registers: delta = 1 + lane + 64k ---
  float wlr[8], wfr[8], wbr[8];
#pragma unroll
  for (int k = 0; k < 8; ++k) {
    int d = 1 + lane + (k << 6);    // max 512 < WSZ
    wlr[k] = Wl[d]; wfr[k] = Wf[d]; wbr[k] = Wb[d];
  }
  const float W0l = Wl[0], W0f = Wf[0], W0b = Wb[0];

  // --- initial state (replicated across lanes) ---
  const int hb = node * POP * 4;
  float V0 = hx[hb + 0], V1 = hx[hb + 4], V2 = hx[hb + 8];
  float E0 = hx[hb + 1], E1 = hx[hb + 5], E2 = hx[hb + 9];
  float I0 = hx[hb + 2], I1 = hx[hb + 6], I2 = hx[hb + 10];
  float N0 = hx[hb + 3], N1 = hx[hb + 7], N2 = hx[hb + 11];
  float sPm1 = hE[node * DMAX];     // "s(-1)" = B[PAD+DMAX-1]

  // --- prologue: P(0) over delta>=1, reads base = c-1-lane (c=PAD+DMAX-1) ---
  int rbase = PAD + DMAX - 2 - lane;
  float Pl, Pf, Pb;
  {
    float pa = 0.f, pf2 = 0.f, pb2 = 0.f;
    if (small) {
#pragma unroll
      for (int k = 0; k < 2; ++k) {
        float e = B[rbase - (k << 6)];
        pa = fmaf(wlr[k], e, pa); pf2 = fmaf(wfr[k], e, pf2); pb2 = fmaf(wbr[k], e, pb2);
      }
    } else {
#pragma unroll
      for (int k = 0; k < 8; ++k) {
        float e = B[rbase - (k << 6)];
        pa = fmaf(wlr[k], e, pa); pf2 = fmaf(wfr[k], e, pf2); pb2 = fmaf(wbr[k], e, pb2);
      }
    }
    wave_reduce3(pa, pf2, pb2);
    Pl = pa; Pf = pf2; Pb = pb2;
  }
  rbase += 1;   // now base for reads issued during step 0 (-> P(1))

  int t = 0;
  for (int tr = 0; tr < TRS; ++tr) {
    float u_tr = (lane < STEPS) ? u_lds[lane * TRS + tr] : 0.f;  // pre-scaled by uk
    for (int st = 0; st < STEPS; ++st) {
      // 1) issue reads for P(t+1) (window ends at s(t-1), written last step)
      float ev[8];
      if (small) {
        ev[0] = B[rbase]; ev[1] = B[rbase - 64];
      } else {
#pragma unroll
        for (int k = 0; k < 8; ++k) ev[k] = B[rbase - (k << 6)];
      }

      // 2) sigmoids / Mg factors from V(t)
      float sE = rcp_(1.f + __expf(fmaf(nps, V0, psVR)));
      float sI = rcp_(1.f + __expf(fmaf(nps, V1, psVR)));
      float sP = rcp_(1.f + __expf(fmaf(nps, V2, psVR)));
      float m0 = rcp_(fmaf(0.2f, __expf(nam * V0), 1.f));
      float m1 = rcp_(fmaf(0.2f, __expf(nam * V1), 1.f));
      float m2 = rcp_(fmaf(0.2f, __expf(nam * V2), 1.f));

      // 3) coupling terms from precomputed partials
      float al = fmaf(W0l, sPm1, Pl);
      float af = fmaf(W0f, sPm1, Pf);
      float ab = fmaf(W0b, sPm1, Pb);
      float lr_l = g_l * (al - rs_l * sP);
      float lr_f = g_f * (af - rs_f * sP);
      float lr_b = g_b * (ab - rs_b * sP);
      float u = __builtin_bit_cast(
          float, __builtin_amdgcn_readlane(__builtin_bit_cast(int, u_tr), st));

      float ex0 = g_gE * sP + lr_l + u;
      float ex1 = g_gE_sc * sE + lr_b;
      float ex2 = g_k * sE + lr_f + u;
      float in0 = g_gI * sI, in1 = g_gI_sc * sI;
      float nm0 = g_gN * sP + lr_l;
      float nm1 = g_gN_sc * sE;
      float nm2 = g_gN * sE;

      // 4) membrane + conductance updates
      float dV0 = gLp * (-VL - V0) + E0 * (VE - V0) + I0 * (-VI - V0) +
                  N0 * m0 * (VNMDA - V0);
      float dV1 = gLp * (-VL - V1) + E1 * (VE - V1) + I1 * (-VI - V1) +
                  N1 * m1 * (VNMDA - V1);
      float dV2 = gLp * (-VL - V2) + E2 * (VE - V2) + I2 * (-VI - V2) +
                  N2 * m2 * (VNMDA - V2);
      V0 = fmaf(DTC, dV0, V0); V1 = fmaf(DTC, dV1, V1); V2 = fmaf(DTC, dV2, V2);
      E0 += dk * (ex0 - E0); E1 += dk * (ex1 - E1); E2 += dk * (ex2 - E2);
      I0 += dk * (in0 - I0); I1 += dk * (in1 - I1); I2 += dk * (in0 - I2);
      N0 += dk * (nm0 - N0); N1 += dk * (nm1 - N1); N2 += dk * (nm2 - N2);

      // 5) append s(t); lanes!=0 scatter to dummy region (no exec juggling)
      int waddr = (lane == 0) ? (PAD + DMAX + t) : (HIST + lane);
      B[waddr] = sP;
      sPm1 = sP;

      // 6) conv FMAs + reduce -> P(t+1) (latency hidden behind next step)
      float pa = 0.f, pf2 = 0.f, pb2 = 0.f;
      if (small) {
        pa = fmaf(wlr[0], ev[0], fmaf(wlr[1], ev[1], 0.f));
        pf2 = fmaf(wfr[0], ev[0], fmaf(wfr[1], ev[1], 0.f));
        pb2 = fmaf(wbr[0], ev[0], fmaf(wbr[1], ev[1], 0.f));
      } else {
#pragma unroll
        for (int k = 0; k < 8; ++k) {
          pa = fmaf(wlr[k], ev[k], pa);
          pf2 = fmaf(wfr[k], ev[k], pf2);
          pb2 = fmaf(wbr[k], ev[k], pb2);
        }
      }
      wave_reduce3(pa, pf2, pb2);
      Pl = pa; Pf = pf2; Pb = pb2;

      rbase += 1;
      t += 1;
    }
    if (lane == 0) vsnap[tr * NODE + node] = V2;
  }
}

// ---------------------------------------------------------------------------
// Kernel C: EEG readout, 4 waves split the n-dimension.
// ---------------------------------------------------------------------------
__global__ __launch_bounds__(256) void eeg_kernel(
    const float* __restrict__ lm, const float* __restrict__ vsnap,
    const float* __restrict__ theta, float* __restrict__ out) {
  int tr = blockIdx.x;
  __shared__ float cm[NODE];
  __shared__ float vs[NODE];
  __shared__ float part[4][OUT];
  int tid = threadIdx.x;
  for (int n = tid; n < NODE; n += 256) {
    float s = 0.f;
    for (int o = 0; o < OUT; ++o) s += lm[o * NODE + n];
    cm[n] = s * (1.f / OUT);
    vs[n] = vsnap[tr * NODE + n];
  }
  __syncthreads();
  int o = tid & 63, w = tid >> 6;
  float acc = 0.f;
  for (int n = w * 100; n < w * 100 + 100; ++n)
    acc = fmaf(lm[o * NODE + n] - cm[n], vs[n], acc);
  part[w][o] = acc;
  __syncthreads();
  if (tid < OUT) {
    float cy0 = theta[22], y0 = theta[19];
    out[tr * OUT + tid] =
        cy0 * (part[0][tid] + part[1][tid] + part[2][tid] + part[3][tid]) - y0;
  }
}

extern "C" void kernel_launch(void* const* d_in, const int* in_sizes, int n_in,
                              void* d_out, int out_size, void* d_ws, size_t ws_size,
                              hipStream_t stream) {
  const float* external = (const float*)d_in[0];
  const float* hx       = (const float*)d_in[1];
  const float* hE       = (const float*)d_in[2];
  const float* sc       = (const float*)d_in[3];
  const float* dist     = (const float*)d_in[4];
  const float* wbb      = (const float*)d_in[5];
  const float* wff      = (const float*)d_in[6];
  const float* wll      = (const float*)d_in[7];
  const float* lm       = (const float*)d_in[8];
  const float* theta    = (const float*)d_in[9];
  float* out = (float*)d_out;

  float* acc = (float*)d_ws;
  float* vsnap = acc + 16;

  hipMemsetAsync(d_ws, 0, 16 * sizeof(float), stream);
  ssq_kernel<<<(NODE * NODE + 255) / 256, 256, 0, stream>>>(wbb, wff, wll, sc, acc);
  sim_kernel<<<NODE, 64, 0, stream>>>(external, hx, hE, sc, dist, wbb, wff, wll,
                                      theta, acc, vsnap);
  eeg_kernel<<<TRS, 256, 0, stream>>>(lm, vsnap, theta, out);
}

// Round 4
// 190.307 us; speedup vs baseline: 2.1352x; 1.4015x over previous
//
#include <hip/hip_runtime.h>
#include <type_traits>

#define NODE 400
#define POP 3
#define TRS 40
#define STEPS 10
#define DMAX 500
#define OUT 64
#define DT 0.1f
#define JPL 7           // ceil(NODE/64) j-indices per lane
#define WSTR 512        // per-stream W bin stride (delta in [0,511])

__device__ __forceinline__ float relu_(float x) { return x > 0.f ? x : 0.f; }
__device__ __forceinline__ float rcp_(float x) { return __builtin_amdgcn_rcpf(x); }
__device__ __forceinline__ float rlane_(float v, int l) {
  return __builtin_bit_cast(float, __builtin_amdgcn_readlane(__builtin_bit_cast(int, v), l));
}

// ---- DPP wave64 reduction: row_shr 1/2/4/8 + row_bcast15/31, total in lane63.
template <int CTRL>
__device__ __forceinline__ float dpp_mov(float x) {
  int r = __builtin_amdgcn_update_dpp(0, __builtin_bit_cast(int, x), CTRL,
                                      0xf, 0xf, true);
  return __builtin_bit_cast(float, r);
}
template <int CTRL>
__device__ __forceinline__ int dpp_movi(int x) {
  return __builtin_amdgcn_update_dpp(0, x, CTRL, 0xf, 0xf, true);
}

__device__ __forceinline__ void wave_reduce3(float& a, float& b, float& c) {
  a += dpp_mov<0x111>(a); b += dpp_mov<0x111>(b); c += dpp_mov<0x111>(c);
  a += dpp_mov<0x112>(a); b += dpp_mov<0x112>(b); c += dpp_mov<0x112>(c);
  a += dpp_mov<0x114>(a); b += dpp_mov<0x114>(b); c += dpp_mov<0x114>(c);
  a += dpp_mov<0x118>(a); b += dpp_mov<0x118>(b); c += dpp_mov<0x118>(c);
  a += dpp_mov<0x142>(a); b += dpp_mov<0x142>(b); c += dpp_mov<0x142>(c);
  a += dpp_mov<0x143>(a); b += dpp_mov<0x143>(b); c += dpp_mov<0x143>(c);
  a = rlane_(a, 63); b = rlane_(b, 63); c = rlane_(c, 63);
}

__device__ __forceinline__ int wave_max_int(int x) {
  x = max(x, dpp_movi<0x111>(x));
  x = max(x, dpp_movi<0x112>(x));
  x = max(x, dpp_movi<0x114>(x));
  x = max(x, dpp_movi<0x118>(x));
  x = max(x, dpp_movi<0x142>(x));
  x = max(x, dpp_movi<0x143>(x));
  return __builtin_amdgcn_readlane(x, 63);
}

// ---------------------------------------------------------------------------
// Kernel A: Frobenius sum-of-squares partials (64 blocks, no atomics).
// part[b]=||exp(w_bb)*sc||^2 partial, part[64+b]=ff, part[128+b]=ll-sym.
// ---------------------------------------------------------------------------
__global__ __launch_bounds__(256) void ssq_kernel(
    const float* __restrict__ wbb, const float* __restrict__ wff,
    const float* __restrict__ wll, const float* __restrict__ sc,
    float* __restrict__ part) {
  float eb = 0.f, ef = 0.f, el = 0.f;
  for (int idx = blockIdx.x * 256 + threadIdx.x; idx < NODE * NODE;
       idx += 64 * 256) {
    int i = idx / NODE, j = idx - i * NODE;
    int ji = j * NODE + i;
    float scij = sc[idx];
    float b = expf(wbb[idx]) * scij;
    float f = expf(wff[idx]) * scij;
    float l = 0.5f * (expf(wll[idx]) * scij + expf(wll[ji]) * sc[ji]);
    eb = fmaf(b, b, eb); ef = fmaf(f, f, ef); el = fmaf(l, l, el);
  }
  wave_reduce3(eb, ef, el);
  __shared__ float red[3][4];
  int lane = threadIdx.x & 63, wv = threadIdx.x >> 6;
  if (lane == 0) { red[0][wv] = eb; red[1][wv] = ef; red[2][wv] = el; }
  __syncthreads();
  if (threadIdx.x == 0) {
    part[blockIdx.x]       = red[0][0] + red[0][1] + red[0][2] + red[0][3];
    part[64 + blockIdx.x]  = red[1][0] + red[1][1] + red[1][2] + red[1][3];
    part[128 + blockIdx.x] = red[2][0] + red[2][1] + red[2][2] + red[2][3];
  }
}

// ---------------------------------------------------------------------------
// Kernel B: per-node simulation, SCATTER form (no per-step reduction).
// s(t) contributes W[delta]*s(t) into P(t+1+delta). Lane L owns future steps
// T == L (mod 64), NB register banks cover delta in [0, 64*NB-1]. Harvest of
// al(t) = 3 readlanes from the owning lane (settled one step earlier).
// No history buffer, no per-step LDS writes, no per-step wave reduction.
// ---------------------------------------------------------------------------
__global__ __launch_bounds__(64) void sim_kernel(
    const float* __restrict__ external, const float* __restrict__ hx,
    const float* __restrict__ hE, const float* __restrict__ sc,
    const float* __restrict__ dist, const float* __restrict__ wbb,
    const float* __restrict__ wff, const float* __restrict__ wll,
    const float* __restrict__ theta, const float* __restrict__ part,
    float* __restrict__ vsnap) {
  const int node = blockIdx.x;
  const int lane = threadIdx.x;

  __shared__ float Wall[3 * WSTR];   // Wl | Wf | Wb delay bins
  __shared__ float hE_lds[DMAX];
  __shared__ float u_lds[STEPS * TRS];

  // --- global norm sums from ssq partials (one DPP reduce) ---
  float sb = part[lane], sf = part[64 + lane], sl = part[128 + lane];
  wave_reduce3(sb, sf, sl);
  const float inv_nb = 1.f / sqrtf(sb);
  const float inv_nf = 1.f / sqrtf(sf);
  const float inv_nl = 1.f / sqrtf(sl);

  // --- parameters ---
  const float VL = relu_(theta[0]), VI = relu_(theta[1]);
  const float VE = relu_(theta[2]), VNMDA = relu_(theta[3]);
  const float alpha_mg = relu_(theta[4]), VR = relu_(theta[5]);
  const float pi_sigma = relu_(theta[6]);
  const float gLp = relu_(theta[7]), Cc = relu_(theta[8]), kappa = relu_(theta[9]);
  const float g_gE = relu_(theta[10]), g_gE_sc = relu_(theta[11]);
  const float g_gI = relu_(theta[12]), g_gI_sc = relu_(theta[13]);
  const float g_gN = relu_(theta[14]), g_gN_sc = relu_(theta[15]);
  const float g_k = relu_(theta[16]);
  const float mu = 0.1f + relu_(theta[20]);
  const float uk = relu_(theta[21]) * theta[23];
  const float g_l = relu_(theta[24]), g_f = relu_(theta[25]), g_b = relu_(theta[26]);
  const float DTC = DT / Cc;
  const float dk = DT * kappa;
  const float nps = -pi_sigma, psVR = pi_sigma * VR;
  const float nam = -alpha_mg;

  // pre-scaled dynamics constants (dk folded in)
  const float dk1  = 1.f - dk;
  const float cA   = dk * g_l;                      // * al (shared E0/N0)
  const float cF   = dk * g_f;                      // * af
  const float cB   = dk * g_b;                      // * ab
  const float cE0s = dk * g_gE;                     // minus cA*rs_l later
  const float cE1e = dk * g_gE_sc;
  const float cE2e = dk * g_k;
  const float cI0  = dk * g_gI;
  const float cI1  = dk * g_gI_sc;
  const float cN0s = dk * g_gN;                     // minus cA*rs_l later
  const float cN1  = dk * g_gN_sc;
  const float cN2  = dk * g_gN;
  const float gLVL = gLp * VL;

  // --- stage LDS: zero W bins, history, pre-scaled external drive ---
  for (int k = lane; k < 3 * WSTR; k += 64) Wall[k] = 0.f;
  for (int d = lane; d < DMAX; d += 64) hE_lds[d] = hE[node * DMAX + d];
  const float ukdk = dk * uk;
  for (int t = lane; t < STEPS * TRS; t += 64)
    u_lds[t] = ukdk * external[node * STEPS * TRS + t];

  // --- bin weights by delay (LDS float atomics), row sums, max delay ---
  float rl = 0.f, rf = 0.f, rb = 0.f;
  int mymax = 0;
#pragma unroll
  for (int kj = 0; kj < JPL; ++kj) {
    int j = lane + kj * 64;
    if (j < NODE) {
      int ij = node * NODE + j;
      int ji = j * NODE + node;
      float scij = sc[ij];
      float vb = expf(wbb[ij]) * scij * inv_nb;
      float vf = expf(wff[ij]) * scij * inv_nf;
      float vl = 0.5f * (expf(wll[ij]) * scij + expf(wll[ji]) * sc[ji]) * inv_nl;
      int dd = (int)(dist[ij] / mu);
      dd = min(max(dd, 0), DMAX - 1);
      atomicAdd(&Wall[dd], vl);
      atomicAdd(&Wall[WSTR + dd], vf);
      atomicAdd(&Wall[2 * WSTR + dd], vb);
      rl += vl; rf += vf; rb += vb;
      mymax = max(mymax, dd);
    }
  }
  wave_reduce3(rl, rf, rb);
  const float rs_l = rl, rs_f = rf, rs_b = rb;
  const int maxd = wave_max_int(mymax);
  const int nb = (maxd >> 6) + 1;   // banks needed (<=8 since maxd<=499)

  // delta=0 weight handled via registers; zero the bin so scatter reads 0
  const float W0l = Wall[0], W0f = Wall[WSTR], W0b = Wall[2 * WSTR];
  if (lane < 3) Wall[lane * WSTR] = 0.f;   // in-order within wave

  const float cE0s2 = cE0s - cA * rs_l;    // sP coefficients, lr folded
  const float cN0s2 = cN0s - cA * rs_l;
  const float cE1s = -cB * rs_b;
  const float cE2s = -cF * rs_f;

  // --- initial state (replicated across lanes) ---
  const int hb = node * POP * 4;
  float V0 = hx[hb + 0], V1 = hx[hb + 4], V2 = hx[hb + 8];
  float E0 = hx[hb + 1], E1 = hx[hb + 5], E2 = hx[hb + 9];
  float I0 = hx[hb + 2], I1 = hx[hb + 6], I2 = hx[hb + 10];
  float N0 = hx[hb + 3], N1 = hx[hb + 7], N2 = hx[hb + 11];
  float sPm1 = hE[node * DMAX];   // s(-1) = hE[0]

  auto core = [&](auto nbtag) {
    constexpr int NB = decltype(nbtag)::value;
    // --- prologue: history contributions. Lane L bank k targets T=L+64k.
    // P(T) += W[d]*s(T-1-d) for T-1-d < 0, i.e. d>=T, s(T-1-d)=hE[d-T].
    float Pl[NB], Pf[NB], Pb[NB];
#pragma unroll
    for (int k = 0; k < NB; ++k) { Pl[k] = 0.f; Pf[k] = 0.f; Pb[k] = 0.f; }
    for (int d = 1; d <= maxd; ++d) {
      float wl_ = Wall[d], wf_ = Wall[WSTR + d], wb_ = Wall[2 * WSTR + d];
#pragma unroll
      for (int k = 0; k < NB; ++k) {
        int T = lane + (k << 6);
        int idx = d - T;
        bool ok = idx >= 0;
        float h = hE_lds[ok ? idx : 0];
        h = ok ? h : 0.f;
        Pl[k] = fmaf(wl_, h, Pl[k]);
        Pf[k] = fmaf(wf_, h, Pf[k]);
        Pb[k] = fmaf(wb_, h, Pb[k]);
      }
    }

    int tl = 0;   // t mod 64 (uniform)
    for (int tr = 0; tr < TRS; ++tr) {
      float u_tr = (lane < STEPS) ? u_lds[lane * TRS + tr] : 0.f;
#pragma unroll
      for (int st = 0; st < STEPS; ++st) {
        // 1) harvest al/af/ab from owning lane (settled last step)
        float al = fmaf(W0l, sPm1, rlane_(Pl[0], tl));
        float af = fmaf(W0f, sPm1, rlane_(Pf[0], tl));
        float ab = fmaf(W0b, sPm1, rlane_(Pb[0], tl));

        // 2) rotate banks on the consuming lane
        bool cons = (lane == tl);
#pragma unroll
        for (int k = 0; k < NB - 1; ++k) {
          Pl[k] = cons ? Pl[k + 1] : Pl[k];
          Pf[k] = cons ? Pf[k + 1] : Pf[k];
          Pb[k] = cons ? Pb[k + 1] : Pb[k];
        }
        Pl[NB - 1] = cons ? 0.f : Pl[NB - 1];
        Pf[NB - 1] = cons ? 0.f : Pf[NB - 1];
        Pb[NB - 1] = cons ? 0.f : Pb[NB - 1];

        // 3) issue W reads for this step's scatter (slack = dynamics below)
        int d1 = (lane - tl - 1) & 63;
        float wsl[NB], wsf[NB], wsb[NB];
#pragma unroll
        for (int k = 0; k < NB; ++k) {
          wsl[k] = Wall[d1 + (k << 6)];
          wsf[k] = Wall[WSTR + d1 + (k << 6)];
          wsb[k] = Wall[2 * WSTR + d1 + (k << 6)];
        }

        // 4) dynamics (replicated)
        float sE = rcp_(1.f + __expf(fmaf(nps, V0, psVR)));
        float sI = rcp_(1.f + __expf(fmaf(nps, V1, psVR)));
        float sP = rcp_(1.f + __expf(fmaf(nps, V2, psVR)));
        float m0 = rcp_(fmaf(0.2f, __expf(nam * V0), 1.f));
        float m1 = rcp_(fmaf(0.2f, __expf(nam * V1), 1.f));
        float m2 = rcp_(fmaf(0.2f, __expf(nam * V2), 1.f));
        float U = rlane_(u_tr, st);            // already dk*uk scaled

        float t1 = cA * al, t2 = cF * af, t3 = cB * ab;
        float nE0 = fmaf(dk1, E0, fmaf(cE0s2, sP, t1 + U));
        float nE1 = fmaf(dk1, E1, fmaf(cE1e, sE, fmaf(cE1s, sP, t3)));
        float nE2 = fmaf(dk1, E2, fmaf(cE2e, sE, fmaf(cE2s, sP, t2 + U)));
        float pI = cI0 * sI;
        float nI0 = fmaf(dk1, I0, pI);
        float nI1 = fmaf(dk1, I1, cI1 * sI);
        float nI2 = fmaf(dk1, I2, pI);
        float nN0 = fmaf(dk1, N0, fmaf(cN0s2, sP, t1));
        float nN1 = fmaf(dk1, N1, cN1 * sE);
        float nN2 = fmaf(dk1, N2, cN2 * sE);

        float Nm0 = N0 * m0, Nm1 = N1 * m1, Nm2 = N2 * m2;
        float R0 = fmaf(E0, VE, fmaf(Nm0, VNMDA, fmaf(I0, -VI, -gLVL)));
        float R1 = fmaf(E1, VE, fmaf(Nm1, VNMDA, fmaf(I1, -VI, -gLVL)));
        float R2 = fmaf(E2, VE, fmaf(Nm2, VNMDA, fmaf(I2, -VI, -gLVL)));
        float S0 = gLp + E0 + I0 + Nm0;
        float S1 = gLp + E1 + I1 + Nm1;
        float S2 = gLp + E2 + I2 + Nm2;
        V0 = fmaf(DTC, fmaf(-S0, V0, R0), V0);
        V1 = fmaf(DTC, fmaf(-S1, V1, R1), V1);
        V2 = fmaf(DTC, fmaf(-S2, V2, R2), V2);
        E0 = nE0; E1 = nE1; E2 = nE2;
        I0 = nI0; I1 = nI1; I2 = nI2;
        N0 = nN0; N1 = nN1; N2 = nN2;

        // 5) scatter s(t) into future partials (off critical path)
#pragma unroll
        for (int k = 0; k < NB; ++k) {
          Pl[k] = fmaf(wsl[k], sP, Pl[k]);
          Pf[k] = fmaf(wsf[k], sP, Pf[k]);
          Pb[k] = fmaf(wsb[k], sP, Pb[k]);
        }
        sPm1 = sP;
        tl = (tl + 1) & 63;
      }
      if (lane == 0) vsnap[tr * NODE + node] = V2;
    }
  };

  if (nb <= 2) core(std::integral_constant<int, 2>{});
  else         core(std::integral_constant<int, 8>{});
}

// ---------------------------------------------------------------------------
// Kernel C: EEG readout, 4 waves split the n-dimension.
// ---------------------------------------------------------------------------
__global__ __launch_bounds__(256) void eeg_kernel(
    const float* __restrict__ lm, const float* __restrict__ vsnap,
    const float* __restrict__ theta, float* __restrict__ out) {
  int tr = blockIdx.x;
  __shared__ float cm[NODE];
  __shared__ float vs[NODE];
  __shared__ float partl[4][OUT];
  int tid = threadIdx.x;
  for (int n = tid; n < NODE; n += 256) {
    float s = 0.f;
    for (int o = 0; o < OUT; ++o) s += lm[o * NODE + n];
    cm[n] = s * (1.f / OUT);
    vs[n] = vsnap[tr * NODE + n];
  }
  __syncthreads();
  int o = tid & 63, w = tid >> 6;
  float acc = 0.f;
  for (int n = w * 100; n < w * 100 + 100; ++n)
    acc = fmaf(lm[o * NODE + n] - cm[n], vs[n], acc);
  partl[w][o] = acc;
  __syncthreads();
  if (tid < OUT) {
    float cy0 = theta[22], y0 = theta[19];
    out[tr * OUT + tid] =
        cy0 * (partl[0][tid] + partl[1][tid] + partl[2][tid] + partl[3][tid]) - y0;
  }
}

extern "C" void kernel_launch(void* const* d_in, const int* in_sizes, int n_in,
                              void* d_out, int out_size, void* d_ws, size_t ws_size,
                              hipStream_t stream) {
  const float* external = (const float*)d_in[0];
  const float* hx       = (const float*)d_in[1];
  const float* hE       = (const float*)d_in[2];
  const float* sc       = (const float*)d_in[3];
  const float* dist     = (const float*)d_in[4];
  const float* wbb      = (const float*)d_in[5];
  const float* wff      = (const float*)d_in[6];
  const float* wll      = (const float*)d_in[7];
  const float* lm       = (const float*)d_in[8];
  const float* theta    = (const float*)d_in[9];
  float* out = (float*)d_out;

  float* vsnap = (float*)d_ws;               // TRS*NODE
  float* part  = vsnap + TRS * NODE;         // 3*64 ssq partials

  ssq_kernel<<<64, 256, 0, stream>>>(wbb, wff, wll, sc, part);
  sim_kernel<<<NODE, 64, 0, stream>>>(external, hx, hE, sc, dist, wbb, wff, wll,
                                      theta, part, vsnap);
  eeg_kernel<<<TRS, 256, 0, stream>>>(lm, vsnap, theta, out);
}